// Round 17
// baseline (86.785 us; speedup 1.0000x reference)
//
#include <hip/hip_runtime.h>
#include <stdint.h>

#define DCH 64
#define KC 512
#define KHALF 256
#define HWSZ 4096
#define THETA 1e-4f
#define POSB 512      // positions per tile (16 waves x 32)
#define BLOCK 1024
#define NPOS 131072
#define PADW 65       // rescue LDS row stride (floats): conflict-free

typedef __attribute__((ext_vector_type(8))) short short8v;
typedef __attribute__((ext_vector_type(4))) float floatx4;

// d_ws layout (bytes)
#define WS_WHS   0                        // 512*64 bf16 hi, SWIZZLED rows
#define WS_WLS   65536                    // 512*64 bf16 lo, SWIZZLED rows
#define WS_WNORM 131072                   // 512 f32 (numpy-pairwise exact)
#define WS_CNT   133120                   // int
#define WS_LIST  133184                   // up to 131072 int
#define WS_NEED  (133184 + 131072 * 4)    // 657472: full-image path
// split-K partials (2 halves x NPOS each)
#define WS_PM1   657472
#define WS_PM2   (657472 + 1048576)
#define WS_PI    (657472 + 2097152)
#define WS_NEED_SPLIT (657472 + 3145728)  // ~3.63 MB

__device__ __forceinline__ uint16_t f2bf_rne(float x) {
  uint32_t u = __float_as_uint(x);
  uint32_t r = (u + 0x7fffu + ((u >> 16) & 1u)) >> 16;
  return (uint16_t)r;
}
__device__ __forceinline__ float bf2f(uint16_t b) {
  return __uint_as_float(((uint32_t)b) << 16);
}

// numpy pairwise_sum of squares, 64 elems (fp-contract off)
__device__ __forceinline__ float pairwise_sq64(const float* __restrict__ a) {
#pragma clang fp contract(off)
  float r0 = a[0]*a[0], r1 = a[1]*a[1], r2 = a[2]*a[2], r3 = a[3]*a[3];
  float r4 = a[4]*a[4], r5 = a[5]*a[5], r6 = a[6]*a[6], r7 = a[7]*a[7];
#pragma unroll
  for (int i = 8; i < 64; i += 8) {
    r0 += a[i+0]*a[i+0]; r1 += a[i+1]*a[i+1];
    r2 += a[i+2]*a[i+2]; r3 += a[i+3]*a[i+3];
    r4 += a[i+4]*a[i+4]; r5 += a[i+5]*a[i+5];
    r6 += a[i+6]*a[i+6]; r7 += a[i+7]*a[i+7];
  }
  return ((r0+r1)+(r2+r3)) + ((r4+r5)+(r6+r7));
}

// Load 8 Z elements (stride HWSZ), bf16-split element-wise.
__device__ __forceinline__ void load_frag(const float* __restrict__ p,
                                          short8v& vh, short8v& vl) {
#pragma unroll
  for (int j = 0; j < 8; ++j) {
    const float v = p[(size_t)j * HWSZ];
    const uint16_t hb = f2bf_rne(v);
    vh[j] = (short)hb;
    vl[j] = (short)f2bf_rne(v - bf2f(hb));
  }
}

// ---------- prep: W -> bf16 split (SWIZZLED image) + exact wnorm ----------
__global__ __launch_bounds__(64) void vq_prep(const float* __restrict__ W,
                                              char* __restrict__ ws) {
  const int c = blockIdx.x * 64 + threadIdx.x;   // 0..511
  const float* __restrict__ wr = W + c * DCH;
  float a[64];
#pragma unroll
  for (int i = 0; i < 16; ++i) {
    const float4 v = ((const float4*)wr)[i];
    a[4*i+0] = v.x; a[4*i+1] = v.y; a[4*i+2] = v.z; a[4*i+3] = v.w;
  }
  ((float*)(ws + WS_WNORM))[c] = pairwise_sq64(a);
  uint16_t* wh = (uint16_t*)(ws + WS_WHS);
  uint16_t* wl = (uint16_t*)(ws + WS_WLS);
#pragma unroll
  for (int gd = 0; gd < 8; ++gd) {
    short8v vh, vl;
#pragma unroll
    for (int e = 0; e < 8; ++e) {
      const float v = a[gd * 8 + e];
      const uint16_t hb = f2bf_rne(v);
      vh[e] = (short)hb;
      vl[e] = (short)f2bf_rne(v - bf2f(hb));
    }
    const int go = (gd ^ (c & 7)) << 3;   // swizzled granule slot
    *(short8v*)(wh + c * DCH + go) = vh;
    *(short8v*)(wl + c * DCH + go) = vl;
  }
  if (c == 0) *(int*)(ws + WS_CNT) = 0;
}

// ---------- split-K main: half codebook per block, 2 blocks/CU ----------
// grid 512: bid>>1 = position tile (512 pos), bid&1 = codebook half.
// LDS 66.5 KB -> two blocks co-reside -> 8 waves/SIMD for latency hiding.
// Loop body identical to the validated R12 kernel (bit-identical scores).
__global__ __launch_bounds__(BLOCK) void vq_main_split(const float* __restrict__ Z,
                                                       char* __restrict__ ws,
                                                       int npos) {
  __shared__ uint16_t img[32768];   // 64 KB: hi [0,16384), lo [16384,32768)
  __shared__ float wnlds[KHALF];    // 1 KB

  const int tid = threadIdx.x;
  const int lane = tid & 63;
  const int wv = tid >> 6;                // 0..15
  const int csub = lane & 15;
  const int gsub = lane >> 4;
  const int h = blockIdx.x & 1;           // codebook half
  const int nbase = (blockIdx.x >> 1) * POSB;

  const char* __restrict__ src_hi = (const char*)ws + (size_t)h * 32768;
  const char* __restrict__ src_lo = (const char*)ws + WS_WLS + (size_t)h * 32768;
  const float* __restrict__ wnorm = (const float*)(ws + WS_WNORM);

  // stage the half image: hi 32 KB (2 rounds) + lo 32 KB (2 rounds)
#pragma unroll
  for (int r = 0; r < 2; ++r) {
    const int base = r * 16384 + wv * 1024;   // wave-uniform LDS byte base
    __builtin_amdgcn_global_load_lds((const uint32_t*)(src_hi + base + lane * 16),
                                     (uint32_t*)((char*)img + base), 16, 0, 0);
    __builtin_amdgcn_global_load_lds((const uint32_t*)(src_lo + base + lane * 16),
                                     (uint32_t*)((char*)img + 32768 + base), 16, 0, 0);
  }
  if (tid < 64) {  // wnorm half: 1 KB via wave 0
    __builtin_amdgcn_global_load_lds((const uint32_t*)((const char*)wnorm + h * 1024 + lane * 16),
                                     (uint32_t*)((char*)wnlds), 16, 0, 0);
  }

  short8v ahA0, ahA1, alA0, alA1, ahB0, ahB1, alB0, alB1;
  {
    const int b = nbase >> 12;
    const int hw0 = nbase & 4095;
    const float* zb = Z + (size_t)b * DCH * HWSZ + hw0 + wv * 32 + csub;
    const int dbase = gsub * 8;
    load_frag(zb + (size_t)(dbase +  0) * HWSZ,      ahA0, alA0);
    load_frag(zb + (size_t)(dbase + 32) * HWSZ,      ahA1, alA1);
    load_frag(zb + (size_t)(dbase +  0) * HWSZ + 16, ahB0, alB0);
    load_frag(zb + (size_t)(dbase + 32) * HWSZ + 16, ahB1, alB1);
  }

  float m1A[4], m2A[4], m1B[4], m2B[4];
  int i1A[4], i1B[4];
#pragma unroll
  for (int r = 0; r < 4; ++r) {
    m1A[r] = 3.4e38f; m2A[r] = 3.4e38f; i1A[r] = 0;
    m1B[r] = 3.4e38f; m2B[r] = 3.4e38f; i1B[r] = 0;
  }

  __syncthreads();  // half-image + wnorm ready; ONLY barrier.

  const uint16_t* __restrict__ whl = img;            // hi
  const uint16_t* __restrict__ wll = img + 16384;    // lo

  // loop-invariant swizzle slots (row&7 == csub&7; half offset 256 = 0 mod 8)
  const int go0 = (gsub ^ (csub & 7)) << 3;
  const int go1 = ((4 + gsub) ^ (csub & 7)) << 3;

#pragma unroll 8
  for (int kt = 0; kt < KHALF / 16; ++kt) {
    const int cq = kt * 16 + csub;          // row within half (0..255)
    const int cloc = h * KHALF + cq;        // global code index
    const float wn = wnlds[cq];
    const short8v bh0 = *(const short8v*)&whl[cq * DCH + go0];
    const short8v bh1 = *(const short8v*)&whl[cq * DCH + go1];
    const short8v bl0 = *(const short8v*)&wll[cq * DCH + go0];
    const short8v bl1 = *(const short8v*)&wll[cq * DCH + go1];
    const floatx4 zz = {0.f, 0.f, 0.f, 0.f};
    floatx4 cA1 = __builtin_amdgcn_mfma_f32_16x16x32_bf16(ahA0, bh0, zz, 0, 0, 0);
    floatx4 cB1 = __builtin_amdgcn_mfma_f32_16x16x32_bf16(ahB0, bh0, zz, 0, 0, 0);
    floatx4 cA2 = __builtin_amdgcn_mfma_f32_16x16x32_bf16(ahA0, bl0, zz, 0, 0, 0);
    floatx4 cB2 = __builtin_amdgcn_mfma_f32_16x16x32_bf16(ahB0, bl0, zz, 0, 0, 0);
    floatx4 cA3 = __builtin_amdgcn_mfma_f32_16x16x32_bf16(alA0, bh0, zz, 0, 0, 0);
    floatx4 cB3 = __builtin_amdgcn_mfma_f32_16x16x32_bf16(alB0, bh0, zz, 0, 0, 0);
    cA1 = __builtin_amdgcn_mfma_f32_16x16x32_bf16(ahA1, bh1, cA1, 0, 0, 0);
    cB1 = __builtin_amdgcn_mfma_f32_16x16x32_bf16(ahB1, bh1, cB1, 0, 0, 0);
    cA2 = __builtin_amdgcn_mfma_f32_16x16x32_bf16(ahA1, bl1, cA2, 0, 0, 0);
    cB2 = __builtin_amdgcn_mfma_f32_16x16x32_bf16(ahB1, bl1, cB2, 0, 0, 0);
    cA3 = __builtin_amdgcn_mfma_f32_16x16x32_bf16(alA1, bh1, cA3, 0, 0, 0);
    cB3 = __builtin_amdgcn_mfma_f32_16x16x32_bf16(alB1, bh1, cB3, 0, 0, 0);
#pragma unroll
    for (int r = 0; r < 4; ++r) {
      const float sA = fmaf(-2.0f, (cA1[r] + cA2[r]) + cA3[r], wn);
      i1A[r] = (sA < m1A[r]) ? cloc : i1A[r];
      m2A[r] = fminf(fmaxf(sA, m1A[r]), m2A[r]);
      m1A[r] = fminf(sA, m1A[r]);
      const float sB = fmaf(-2.0f, (cB1[r] + cB2[r]) + cB3[r], wn);
      i1B[r] = (sB < m1B[r]) ? cloc : i1B[r];
      m2B[r] = fminf(fmaxf(sB, m1B[r]), m2B[r]);
      m1B[r] = fminf(sB, m1B[r]);
    }
  }

#pragma unroll
  for (int off = 1; off < 16; off <<= 1) {
#pragma unroll
    for (int r = 0; r < 4; ++r) {
      {
        const float om1 = __shfl_xor(m1A[r], off, 64);
        const float om2 = __shfl_xor(m2A[r], off, 64);
        const int oi = __shfl_xor(i1A[r], off, 64);
        const float nm2 = fminf(fmaxf(m1A[r], om1), fminf(m2A[r], om2));
        i1A[r] = (om1 < m1A[r]) ? oi : i1A[r];
        m1A[r] = fminf(m1A[r], om1);
        m2A[r] = nm2;
      }
      {
        const float om1 = __shfl_xor(m1B[r], off, 64);
        const float om2 = __shfl_xor(m2B[r], off, 64);
        const int oi = __shfl_xor(i1B[r], off, 64);
        const float nm2 = fminf(fmaxf(m1B[r], om1), fminf(m2B[r], om2));
        i1B[r] = (om1 < m1B[r]) ? oi : i1B[r];
        m1B[r] = fminf(m1B[r], om1);
        m2B[r] = nm2;
      }
    }
  }
  // write per-half partials (no atomics; combine kernel does the gap test)
  if (csub == 0) {
    float* pm1 = (float*)(ws + WS_PM1) + (size_t)h * npos;
    float* pm2 = (float*)(ws + WS_PM2) + (size_t)h * npos;
    int* pi = (int*)(ws + WS_PI) + (size_t)h * npos;
#pragma unroll
    for (int r = 0; r < 4; ++r) {
      const int posA = nbase + wv * 32 + gsub * 4 + r;
      pm1[posA] = m1A[r]; pm2[posA] = m2A[r]; pi[posA] = i1A[r];
      const int posB = posA + 16;
      pm1[posB] = m1B[r]; pm2[posB] = m2B[r]; pi[posB] = i1B[r];
    }
  }
}

// ---------- combine: merge two half-top-2s, write argmin, flag close calls ----------
__global__ __launch_bounds__(256) void vq_combine(char* __restrict__ ws,
                                                  int* __restrict__ out,
                                                  int npos) {
  const int pos = blockIdx.x * 256 + threadIdx.x;
  if (pos >= npos) return;
  const float* pm1 = (const float*)(ws + WS_PM1);
  const float* pm2 = (const float*)(ws + WS_PM2);
  const int* pi = (const int*)(ws + WS_PI);
  int* cnt = (int*)(ws + WS_CNT);
  int* list = (int*)(ws + WS_LIST);

  const float m1a = pm1[pos], m1b = pm1[npos + pos];
  const float m2a = pm2[pos], m2b = pm2[npos + pos];
  const int ia = pi[pos], ib = pi[npos + pos];
  // half-0 indices < half-1 indices, so strict < keeps numpy first-min-wins
  const int idx = (m1b < m1a) ? ib : ia;
  const float m1 = fminf(m1a, m1b);
  const float m2 = fminf(fmaxf(m1a, m1b), fminf(m2a, m2b));
  out[pos] = idx;
  if (!(m2 - m1 > THETA)) {
    const int slot = atomicAdd(cnt, 1);
    list[slot] = pos;
  }
}

// ---------- full-image main (validated R12, 69.7 us total) — ws fallback ----------
__global__ __launch_bounds__(BLOCK) void vq_main_full(const float* __restrict__ Z,
                                                      char* __restrict__ ws,
                                                      int* __restrict__ out) {
  __shared__ uint16_t img[65536];   // 128 KB
  __shared__ float wnlds[KC];

  const int tid = threadIdx.x;
  const int lane = tid & 63;
  const int wv = tid >> 6;
  const int csub = lane & 15;
  const int gsub = lane >> 4;
  const int nbase = blockIdx.x * POSB;

  const char* __restrict__ img_src = (const char*)ws;
  const float* __restrict__ wnorm = (const float*)(ws + WS_WNORM);
  int* cnt = (int*)(ws + WS_CNT);
  int* list = (int*)(ws + WS_LIST);

#pragma unroll
  for (int r = 0; r < 8; ++r) {
    const int base = r * 16384 + wv * 1024;
    __builtin_amdgcn_global_load_lds((const uint32_t*)(img_src + base + lane * 16),
                                     (uint32_t*)((char*)img + base), 16, 0, 0);
  }
  if (tid < 128) {
    const int base = wv * 1024;
    __builtin_amdgcn_global_load_lds((const uint32_t*)((const char*)wnorm + base + lane * 16),
                                     (uint32_t*)((char*)wnlds + base), 16, 0, 0);
  }

  short8v ahA0, ahA1, alA0, alA1, ahB0, ahB1, alB0, alB1;
  {
    const int b = nbase >> 12;
    const int hw0 = nbase & 4095;
    const float* zb = Z + (size_t)b * DCH * HWSZ + hw0 + wv * 32 + csub;
    const int dbase = gsub * 8;
    load_frag(zb + (size_t)(dbase +  0) * HWSZ,      ahA0, alA0);
    load_frag(zb + (size_t)(dbase + 32) * HWSZ,      ahA1, alA1);
    load_frag(zb + (size_t)(dbase +  0) * HWSZ + 16, ahB0, alB0);
    load_frag(zb + (size_t)(dbase + 32) * HWSZ + 16, ahB1, alB1);
  }

  float m1A[4], m2A[4], m1B[4], m2B[4];
  int i1A[4], i1B[4];
#pragma unroll
  for (int r = 0; r < 4; ++r) {
    m1A[r] = 3.4e38f; m2A[r] = 3.4e38f; i1A[r] = 0;
    m1B[r] = 3.4e38f; m2B[r] = 3.4e38f; i1B[r] = 0;
  }

  __syncthreads();

  const uint16_t* __restrict__ whl = img;
  const uint16_t* __restrict__ wll = img + 32768;
  const int go0 = (gsub ^ (csub & 7)) << 3;
  const int go1 = ((4 + gsub) ^ (csub & 7)) << 3;

#pragma unroll 8
  for (int kt = 0; kt < KC / 16; ++kt) {
    const int cloc = kt * 16 + csub;
    const float wn = wnlds[cloc];
    const short8v bh0 = *(const short8v*)&whl[cloc * DCH + go0];
    const short8v bh1 = *(const short8v*)&whl[cloc * DCH + go1];
    const short8v bl0 = *(const short8v*)&wll[cloc * DCH + go0];
    const short8v bl1 = *(const short8v*)&wll[cloc * DCH + go1];
    const floatx4 zz = {0.f, 0.f, 0.f, 0.f};
    floatx4 cA1 = __builtin_amdgcn_mfma_f32_16x16x32_bf16(ahA0, bh0, zz, 0, 0, 0);
    floatx4 cB1 = __builtin_amdgcn_mfma_f32_16x16x32_bf16(ahB0, bh0, zz, 0, 0, 0);
    floatx4 cA2 = __builtin_amdgcn_mfma_f32_16x16x32_bf16(ahA0, bl0, zz, 0, 0, 0);
    floatx4 cB2 = __builtin_amdgcn_mfma_f32_16x16x32_bf16(ahB0, bl0, zz, 0, 0, 0);
    floatx4 cA3 = __builtin_amdgcn_mfma_f32_16x16x32_bf16(alA0, bh0, zz, 0, 0, 0);
    floatx4 cB3 = __builtin_amdgcn_mfma_f32_16x16x32_bf16(alB0, bh0, zz, 0, 0, 0);
    cA1 = __builtin_amdgcn_mfma_f32_16x16x32_bf16(ahA1, bh1, cA1, 0, 0, 0);
    cB1 = __builtin_amdgcn_mfma_f32_16x16x32_bf16(ahB1, bh1, cB1, 0, 0, 0);
    cA2 = __builtin_amdgcn_mfma_f32_16x16x32_bf16(ahA1, bl1, cA2, 0, 0, 0);
    cB2 = __builtin_amdgcn_mfma_f32_16x16x32_bf16(ahB1, bl1, cB2, 0, 0, 0);
    cA3 = __builtin_amdgcn_mfma_f32_16x16x32_bf16(alA1, bh1, cA3, 0, 0, 0);
    cB3 = __builtin_amdgcn_mfma_f32_16x16x32_bf16(alB1, bh1, cB3, 0, 0, 0);
#pragma unroll
    for (int r = 0; r < 4; ++r) {
      const float sA = fmaf(-2.0f, (cA1[r] + cA2[r]) + cA3[r], wn);
      i1A[r] = (sA < m1A[r]) ? cloc : i1A[r];
      m2A[r] = fminf(fmaxf(sA, m1A[r]), m2A[r]);
      m1A[r] = fminf(sA, m1A[r]);
      const float sB = fmaf(-2.0f, (cB1[r] + cB2[r]) + cB3[r], wn);
      i1B[r] = (sB < m1B[r]) ? cloc : i1B[r];
      m2B[r] = fminf(fmaxf(sB, m1B[r]), m2B[r]);
      m1B[r] = fminf(sB, m1B[r]);
    }
  }

#pragma unroll
  for (int off = 1; off < 16; off <<= 1) {
#pragma unroll
    for (int r = 0; r < 4; ++r) {
      {
        const float om1 = __shfl_xor(m1A[r], off, 64);
        const float om2 = __shfl_xor(m2A[r], off, 64);
        const int oi = __shfl_xor(i1A[r], off, 64);
        const float nm2 = fminf(fmaxf(m1A[r], om1), fminf(m2A[r], om2));
        i1A[r] = (om1 < m1A[r]) ? oi : i1A[r];
        m1A[r] = fminf(m1A[r], om1);
        m2A[r] = nm2;
      }
      {
        const float om1 = __shfl_xor(m1B[r], off, 64);
        const float om2 = __shfl_xor(m2B[r], off, 64);
        const int oi = __shfl_xor(i1B[r], off, 64);
        const float nm2 = fminf(fmaxf(m1B[r], om1), fminf(m2B[r], om2));
        i1B[r] = (om1 < m1B[r]) ? oi : i1B[r];
        m1B[r] = fminf(m1B[r], om1);
        m2B[r] = nm2;
      }
    }
  }
  if (csub == 0) {
#pragma unroll
    for (int r = 0; r < 4; ++r) {
      const int posA = nbase + wv * 32 + gsub * 4 + r;
      out[posA] = i1A[r];
      if (!(m2A[r] - m1A[r] > THETA)) {
        const int slot = atomicAdd(cnt, 1);
        list[slot] = posA;
      }
      const int posB = posA + 16;
      out[posB] = i1B[r];
      if (!(m2B[r] - m1B[r] > THETA)) {
        const int slot = atomicAdd(cnt, 1);
        list[slot] = posB;
      }
    }
  }
}

// ---------- rescue: LDS-staged W, conflict-free; bit-exact numpy order ----------
__global__ __launch_bounds__(256) void vq_rescue(const float* __restrict__ Z,
                                                 const float* __restrict__ W,
                                                 char* __restrict__ ws,
                                                 int* __restrict__ out) {
  __shared__ float wt[KC * PADW];   // 512 x 65 floats = 133,120 B
  const int cnt = *(const int*)(ws + WS_CNT);
  if (blockIdx.x * 4 >= cnt) return;   // block-uniform early out (before staging)

  const int lane = threadIdx.x & 63;
  const int wv = threadIdx.x >> 6;     // 0..3
  const int wvg = blockIdx.x * 4 + wv;
  const int* list = (const int*)(ws + WS_LIST);
  const float* wnorm = (const float*)(ws + WS_WNORM);

  for (int c = wv; c < KC; c += 4) {
    wt[c * PADW + lane] = W[c * DCH + lane];
  }
  __syncthreads();

  for (int j = wvg; j < cnt; j += 256 * 4) {
    const int pos = list[j];
    const int b = pos >> 12, hw = pos & 4095;
    float z[DCH];
    const float* zb = Z + ((size_t)b * DCH) * HWSZ + hw;
#pragma unroll
    for (int d = 0; d < DCH; ++d) z[d] = zb[(size_t)d * HWSZ];
    const float znorm = pairwise_sq64(z);
    float bm = 3.4e38f;
    int bi = 0;
#pragma unroll 1
    for (int j2 = 0; j2 < 8; ++j2) {
      const int k = j2 * 64 + lane;
      const float* __restrict__ wrow = &wt[k * PADW];  // lane-own row
      float acc = 0.f;
#pragma unroll
      for (int d = 0; d < DCH; ++d) acc = fmaf(z[d], wrow[d], acc);
      const float dist = (znorm - 2.0f * acc) + wnorm[k];
      if (dist < bm) { bm = dist; bi = k; }  // ascending k per lane
    }
#pragma unroll
    for (int off = 32; off >= 1; off >>= 1) {
      const float ov = __shfl_xor(bm, off, 64);
      const int oi = __shfl_xor(bi, off, 64);
      if (ov < bm || (ov == bm && oi < bi)) { bm = ov; bi = oi; }
    }
    if (lane == 0) out[pos] = bi;
  }
}

// ---------- fallback (R4, known exact) if ws too small ----------
__global__ __launch_bounds__(256, 4) void vq_fallback(const float* __restrict__ Z,
                                                      const float* __restrict__ W,
                                                      int* __restrict__ out) {
  __shared__ float wnorm[KC];
  __shared__ float cmin[4][64];
  __shared__ int cidx[4][64];
  const int tid = threadIdx.x;
  for (int c = tid; c < KC; c += 256) wnorm[c] = pairwise_sq64(W + c * DCH);
  const int lane = tid & 63;
  const int wv = __builtin_amdgcn_readfirstlane(tid >> 6);
  const int n = blockIdx.x * 64 + lane;
  float z[DCH];
  {
    const int b = n >> 12, hw = n & 4095;
    const float* zbase = Z + ((size_t)b * DCH) * HWSZ + hw;
#pragma unroll
    for (int d = 0; d < DCH; ++d) z[d] = zbase[(size_t)d * HWSZ];
  }
  const float znorm = pairwise_sq64(z);
  __syncthreads();
  float bmin = 3.4e38f;
  int bidx = 0;
  const int k0 = wv * 128;
#pragma unroll 1
  for (int kk = 0; kk < 128; kk += 8) {
    const int k = k0 + kk;
    const float* wr = W + (size_t)k * DCH;
    float acc[8];
#pragma unroll
    for (int j = 0; j < 8; ++j) acc[j] = 0.0f;
#pragma unroll
    for (int d = 0; d < DCH; ++d) {
      const float zd = z[d];
#pragma unroll
      for (int j = 0; j < 8; ++j) acc[j] = fmaf(zd, wr[j * DCH + d], acc[j]);
    }
#pragma unroll
    for (int j = 0; j < 8; ++j) {
      const float dist = (znorm - 2.0f * acc[j]) + wnorm[k + j];
      if (dist < bmin) { bmin = dist; bidx = k + j; }
    }
  }
  cmin[wv][lane] = bmin;
  cidx[wv][lane] = bidx;
  __syncthreads();
  if (tid < 64) {
    float m = cmin[0][tid];
    int ix = cidx[0][tid];
#pragma unroll
    for (int h = 1; h < 4; ++h) {
      if (cmin[h][tid] < m) { m = cmin[h][tid]; ix = cidx[h][tid]; }
    }
    out[blockIdx.x * 64 + tid] = ix;
  }
}

extern "C" void kernel_launch(void* const* d_in, const int* in_sizes, int n_in,
                              void* d_out, int out_size, void* d_ws, size_t ws_size,
                              hipStream_t stream) {
  const float* Z = (const float*)d_in[0];
  const float* W = (const float*)d_in[1];
  int* out = (int*)d_out;
  char* ws = (char*)d_ws;
  const int npos = in_sizes[0] / DCH;  // 131072

  if (ws_size >= (size_t)WS_NEED_SPLIT) {
    vq_prep<<<8, 64, 0, stream>>>(W, ws);
    vq_main_split<<<(npos / POSB) * 2, BLOCK, 0, stream>>>(Z, ws, npos);
    vq_combine<<<(npos + 255) / 256, 256, 0, stream>>>(ws, out, npos);
    vq_rescue<<<256, 256, 0, stream>>>(Z, W, ws, out);
  } else if (ws_size >= (size_t)WS_NEED) {
    vq_prep<<<8, 64, 0, stream>>>(W, ws);
    vq_main_full<<<npos / POSB, BLOCK, 0, stream>>>(Z, ws, out);
    vq_rescue<<<256, 256, 0, stream>>>(Z, W, ws, out);
  } else {
    vq_fallback<<<npos / 64, 256, 0, stream>>>(Z, W, out);
  }
}

// Round 18
// 77.740 us; speedup vs baseline: 1.1163x; 1.1163x over previous
//
#include <hip/hip_runtime.h>
#include <stdint.h>

#define DCH 64
#define KC 512
#define HWSZ 4096
#define THETA 1e-4f
#define POSB 512      // positions per block (16 waves x 32)
#define BLOCK 1024
#define PADW 65       // rescue LDS row stride (floats): conflict-free
#define RESCUE_BLOCKS 128

typedef __attribute__((ext_vector_type(8))) short short8v;
typedef __attribute__((ext_vector_type(4))) float floatx4;

// d_ws layout (bytes)
#define WS_WHS   0                        // 512*64 bf16 hi, SWIZZLED rows
#define WS_WLS   65536                    // 512*64 bf16 lo, SWIZZLED rows
#define WS_WNORM 131072                   // 512 f32 (numpy-pairwise exact)
#define WS_CNT   133120                   // int
#define WS_LIST  133184                   // up to 131072 int
#define WS_NEED  (133184 + 131072 * 4)

__device__ __forceinline__ uint16_t f2bf_rne(float x) {
  uint32_t u = __float_as_uint(x);
  uint32_t r = (u + 0x7fffu + ((u >> 16) & 1u)) >> 16;
  return (uint16_t)r;
}
__device__ __forceinline__ float bf2f(uint16_t b) {
  return __uint_as_float(((uint32_t)b) << 16);
}

// numpy pairwise_sum of squares, 64 elems (fp-contract off)
__device__ __forceinline__ float pairwise_sq64(const float* __restrict__ a) {
#pragma clang fp contract(off)
  float r0 = a[0]*a[0], r1 = a[1]*a[1], r2 = a[2]*a[2], r3 = a[3]*a[3];
  float r4 = a[4]*a[4], r5 = a[5]*a[5], r6 = a[6]*a[6], r7 = a[7]*a[7];
#pragma unroll
  for (int i = 8; i < 64; i += 8) {
    r0 += a[i+0]*a[i+0]; r1 += a[i+1]*a[i+1];
    r2 += a[i+2]*a[i+2]; r3 += a[i+3]*a[i+3];
    r4 += a[i+4]*a[i+4]; r5 += a[i+5]*a[i+5];
    r6 += a[i+6]*a[i+6]; r7 += a[i+7]*a[i+7];
  }
  return ((r0+r1)+(r2+r3)) + ((r4+r5)+(r6+r7));
}

// Load 8 Z elements (stride HWSZ), bf16-split element-wise.
__device__ __forceinline__ void load_frag(const float* __restrict__ p,
                                          short8v& vh, short8v& vl) {
#pragma unroll
  for (int j = 0; j < 8; ++j) {
    const float v = p[(size_t)j * HWSZ];
    const uint16_t hb = f2bf_rne(v);
    vh[j] = (short)hb;
    vl[j] = (short)f2bf_rne(v - bf2f(hb));
  }
}

// ---------- prep: W -> bf16 split (SWIZZLED image) + exact wnorm ----------
__global__ __launch_bounds__(64) void vq_prep(const float* __restrict__ W,
                                              char* __restrict__ ws) {
  const int c = blockIdx.x * 64 + threadIdx.x;   // 0..511
  const float* __restrict__ wr = W + c * DCH;
  float a[64];
#pragma unroll
  for (int i = 0; i < 16; ++i) {
    const float4 v = ((const float4*)wr)[i];
    a[4*i+0] = v.x; a[4*i+1] = v.y; a[4*i+2] = v.z; a[4*i+3] = v.w;
  }
  ((float*)(ws + WS_WNORM))[c] = pairwise_sq64(a);
  uint16_t* wh = (uint16_t*)(ws + WS_WHS);
  uint16_t* wl = (uint16_t*)(ws + WS_WLS);
#pragma unroll
  for (int gd = 0; gd < 8; ++gd) {
    short8v vh, vl;
#pragma unroll
    for (int e = 0; e < 8; ++e) {
      const float v = a[gd * 8 + e];
      const uint16_t hb = f2bf_rne(v);
      vh[e] = (short)hb;
      vl[e] = (short)f2bf_rne(v - bf2f(hb));
    }
    const int go = (gd ^ (c & 7)) << 3;   // swizzled granule slot
    *(short8v*)(wh + c * DCH + go) = vh;
    *(short8v*)(wl + c * DCH + go) = vl;
  }
  if (c == 0) *(int*)(ws + WS_CNT) = 0;
}

// ---------- main: MFMA scoring + top-2 gap test (R12, validated 69.7us) ----------
// 1024 threads = 16 waves x 32 positions; grid = 256 = 1 block/CU.
// Whole 128 KB split-W image in LDS once, single barrier, barrier-free loop.
__global__ __launch_bounds__(BLOCK) void vq_main(const float* __restrict__ Z,
                                                 char* __restrict__ ws,
                                                 int* __restrict__ out) {
  __shared__ uint16_t img[65536];   // 128 KB: hi [0,32768), lo [32768,65536)
  __shared__ float wnlds[KC];       // 2 KB

  const int tid = threadIdx.x;
  const int lane = tid & 63;
  const int wv = tid >> 6;                // 0..15
  const int csub = lane & 15;
  const int gsub = lane >> 4;
  const int nbase = blockIdx.x * POSB;

  const char* __restrict__ img_src = (const char*)ws;  // 128 KB contiguous
  const float* __restrict__ wnorm = (const float*)(ws + WS_WNORM);
  int* cnt = (int*)(ws + WS_CNT);
  int* list = (int*)(ws + WS_LIST);

#pragma unroll
  for (int r = 0; r < 8; ++r) {
    const int base = r * 16384 + wv * 1024;   // wave-uniform LDS byte base
    __builtin_amdgcn_global_load_lds((const uint32_t*)(img_src + base + lane * 16),
                                     (uint32_t*)((char*)img + base), 16, 0, 0);
  }
  if (tid < 128) {
    const int base = wv * 1024;
    __builtin_amdgcn_global_load_lds((const uint32_t*)((const char*)wnorm + base + lane * 16),
                                     (uint32_t*)((char*)wnlds + base), 16, 0, 0);
  }

  short8v ahA0, ahA1, alA0, alA1, ahB0, ahB1, alB0, alB1;
  {
    const int b = nbase >> 12;
    const int hw0 = nbase & 4095;
    const float* zb = Z + (size_t)b * DCH * HWSZ + hw0 + wv * 32 + csub;
    const int dbase = gsub * 8;
    load_frag(zb + (size_t)(dbase +  0) * HWSZ,      ahA0, alA0);
    load_frag(zb + (size_t)(dbase + 32) * HWSZ,      ahA1, alA1);
    load_frag(zb + (size_t)(dbase +  0) * HWSZ + 16, ahB0, alB0);
    load_frag(zb + (size_t)(dbase + 32) * HWSZ + 16, ahB1, alB1);
  }

  float m1A[4], m2A[4], m1B[4], m2B[4];
  int i1A[4], i1B[4];
#pragma unroll
  for (int r = 0; r < 4; ++r) {
    m1A[r] = 3.4e38f; m2A[r] = 3.4e38f; i1A[r] = 0;
    m1B[r] = 3.4e38f; m2B[r] = 3.4e38f; i1B[r] = 0;
  }

  __syncthreads();  // image + wnorm ready; ONLY barrier.

  const uint16_t* __restrict__ whl = img;            // hi
  const uint16_t* __restrict__ wll = img + 32768;    // lo

  // loop-invariant swizzle slots (cloc&7 == csub&7 since kt*16 % 8 == 0)
  const int go0 = (gsub ^ (csub & 7)) << 3;
  const int go1 = ((4 + gsub) ^ (csub & 7)) << 3;

#pragma unroll 8
  for (int kt = 0; kt < KC / 16; ++kt) {
    const int cloc = kt * 16 + csub;
    const float wn = wnlds[cloc];
    const short8v bh0 = *(const short8v*)&whl[cloc * DCH + go0];
    const short8v bh1 = *(const short8v*)&whl[cloc * DCH + go1];
    const short8v bl0 = *(const short8v*)&wll[cloc * DCH + go0];
    const short8v bl1 = *(const short8v*)&wll[cloc * DCH + go1];
    const floatx4 zz = {0.f, 0.f, 0.f, 0.f};
    floatx4 cA1 = __builtin_amdgcn_mfma_f32_16x16x32_bf16(ahA0, bh0, zz, 0, 0, 0);
    floatx4 cB1 = __builtin_amdgcn_mfma_f32_16x16x32_bf16(ahB0, bh0, zz, 0, 0, 0);
    floatx4 cA2 = __builtin_amdgcn_mfma_f32_16x16x32_bf16(ahA0, bl0, zz, 0, 0, 0);
    floatx4 cB2 = __builtin_amdgcn_mfma_f32_16x16x32_bf16(ahB0, bl0, zz, 0, 0, 0);
    floatx4 cA3 = __builtin_amdgcn_mfma_f32_16x16x32_bf16(alA0, bh0, zz, 0, 0, 0);
    floatx4 cB3 = __builtin_amdgcn_mfma_f32_16x16x32_bf16(alB0, bh0, zz, 0, 0, 0);
    cA1 = __builtin_amdgcn_mfma_f32_16x16x32_bf16(ahA1, bh1, cA1, 0, 0, 0);
    cB1 = __builtin_amdgcn_mfma_f32_16x16x32_bf16(ahB1, bh1, cB1, 0, 0, 0);
    cA2 = __builtin_amdgcn_mfma_f32_16x16x32_bf16(ahA1, bl1, cA2, 0, 0, 0);
    cB2 = __builtin_amdgcn_mfma_f32_16x16x32_bf16(ahB1, bl1, cB2, 0, 0, 0);
    cA3 = __builtin_amdgcn_mfma_f32_16x16x32_bf16(alA1, bh1, cA3, 0, 0, 0);
    cB3 = __builtin_amdgcn_mfma_f32_16x16x32_bf16(alB1, bh1, cB3, 0, 0, 0);
#pragma unroll
    for (int r = 0; r < 4; ++r) {
      const float sA = fmaf(-2.0f, (cA1[r] + cA2[r]) + cA3[r], wn);
      i1A[r] = (sA < m1A[r]) ? cloc : i1A[r];
      m2A[r] = fminf(fmaxf(sA, m1A[r]), m2A[r]);
      m1A[r] = fminf(sA, m1A[r]);
      const float sB = fmaf(-2.0f, (cB1[r] + cB2[r]) + cB3[r], wn);
      i1B[r] = (sB < m1B[r]) ? cloc : i1B[r];
      m2B[r] = fminf(fmaxf(sB, m1B[r]), m2B[r]);
      m1B[r] = fminf(sB, m1B[r]);
    }
  }

#pragma unroll
  for (int off = 1; off < 16; off <<= 1) {
#pragma unroll
    for (int r = 0; r < 4; ++r) {
      {
        const float om1 = __shfl_xor(m1A[r], off, 64);
        const float om2 = __shfl_xor(m2A[r], off, 64);
        const int oi = __shfl_xor(i1A[r], off, 64);
        const float nm2 = fminf(fmaxf(m1A[r], om1), fminf(m2A[r], om2));
        i1A[r] = (om1 < m1A[r]) ? oi : i1A[r];
        m1A[r] = fminf(m1A[r], om1);
        m2A[r] = nm2;
      }
      {
        const float om1 = __shfl_xor(m1B[r], off, 64);
        const float om2 = __shfl_xor(m2B[r], off, 64);
        const int oi = __shfl_xor(i1B[r], off, 64);
        const float nm2 = fminf(fmaxf(m1B[r], om1), fminf(m2B[r], om2));
        i1B[r] = (om1 < m1B[r]) ? oi : i1B[r];
        m1B[r] = fminf(m1B[r], om1);
        m2B[r] = nm2;
      }
    }
  }
  if (csub == 0) {
#pragma unroll
    for (int r = 0; r < 4; ++r) {
      const int posA = nbase + wv * 32 + gsub * 4 + r;
      out[posA] = i1A[r];
      if (!(m2A[r] - m1A[r] > THETA)) {
        const int slot = atomicAdd(cnt, 1);
        list[slot] = posA;
      }
      const int posB = posA + 16;
      out[posB] = i1B[r];
      if (!(m2B[r] - m1B[r] > THETA)) {
        const int slot = atomicAdd(cnt, 1);
        list[slot] = posB;
      }
    }
  }
}

// ---------- rescue: LDS-staged W, conflict-free; bit-exact numpy order ----------
// R18: 128 blocks (was 256) -> half the W-staging traffic; ~4 items/wave at
// typical cnt~2000, still staging-latency dominated.
__global__ __launch_bounds__(256) void vq_rescue(const float* __restrict__ Z,
                                                 const float* __restrict__ W,
                                                 char* __restrict__ ws,
                                                 int* __restrict__ out) {
  __shared__ float wt[KC * PADW];   // 512 x 65 floats = 133,120 B
  const int cnt = *(const int*)(ws + WS_CNT);
  if (blockIdx.x * 4 >= cnt) return;   // block-uniform early out (before staging)

  const int lane = threadIdx.x & 63;
  const int wv = threadIdx.x >> 6;     // 0..3
  const int wvg = blockIdx.x * 4 + wv;
  const int* list = (const int*)(ws + WS_LIST);
  const float* wnorm = (const float*)(ws + WS_WNORM);

  for (int c = wv; c < KC; c += 4) {
    wt[c * PADW + lane] = W[c * DCH + lane];
  }
  __syncthreads();

  for (int j = wvg; j < cnt; j += RESCUE_BLOCKS * 4) {
    const int pos = list[j];
    const int b = pos >> 12, hw = pos & 4095;
    float z[DCH];
    const float* zb = Z + ((size_t)b * DCH) * HWSZ + hw;
#pragma unroll
    for (int d = 0; d < DCH; ++d) z[d] = zb[(size_t)d * HWSZ];
    const float znorm = pairwise_sq64(z);
    float bm = 3.4e38f;
    int bi = 0;
#pragma unroll 1
    for (int j2 = 0; j2 < 8; ++j2) {
      const int k = j2 * 64 + lane;
      const float* __restrict__ wrow = &wt[k * PADW];  // lane-own row
      float acc = 0.f;
#pragma unroll
      for (int d = 0; d < DCH; ++d) acc = fmaf(z[d], wrow[d], acc);
      const float dist = (znorm - 2.0f * acc) + wnorm[k];
      if (dist < bm) { bm = dist; bi = k; }  // ascending k per lane
    }
#pragma unroll
    for (int off = 32; off >= 1; off >>= 1) {
      const float ov = __shfl_xor(bm, off, 64);
      const int oi = __shfl_xor(bi, off, 64);
      if (ov < bm || (ov == bm && oi < bi)) { bm = ov; bi = oi; }
    }
    if (lane == 0) out[pos] = bi;
  }
}

// ---------- fallback (R4, known exact) if ws too small ----------
__global__ __launch_bounds__(256, 4) void vq_fallback(const float* __restrict__ Z,
                                                      const float* __restrict__ W,
                                                      int* __restrict__ out) {
  __shared__ float wnorm[KC];
  __shared__ float cmin[4][64];
  __shared__ int cidx[4][64];
  const int tid = threadIdx.x;
  for (int c = tid; c < KC; c += 256) wnorm[c] = pairwise_sq64(W + c * DCH);
  const int lane = tid & 63;
  const int wv = __builtin_amdgcn_readfirstlane(tid >> 6);
  const int n = blockIdx.x * 64 + lane;
  float z[DCH];
  {
    const int b = n >> 12, hw = n & 4095;
    const float* zbase = Z + ((size_t)b * DCH) * HWSZ + hw;
#pragma unroll
    for (int d = 0; d < DCH; ++d) z[d] = zbase[(size_t)d * HWSZ];
  }
  const float znorm = pairwise_sq64(z);
  __syncthreads();
  float bmin = 3.4e38f;
  int bidx = 0;
  const int k0 = wv * 128;
#pragma unroll 1
  for (int kk = 0; kk < 128; kk += 8) {
    const int k = k0 + kk;
    const float* wr = W + (size_t)k * DCH;
    float acc[8];
#pragma unroll
    for (int j = 0; j < 8; ++j) acc[j] = 0.0f;
#pragma unroll
    for (int d = 0; d < DCH; ++d) {
      const float zd = z[d];
#pragma unroll
      for (int j = 0; j < 8; ++j) acc[j] = fmaf(zd, wr[j * DCH + d], acc[j]);
    }
#pragma unroll
    for (int j = 0; j < 8; ++j) {
      const float dist = (znorm - 2.0f * acc[j]) + wnorm[k + j];
      if (dist < bmin) { bmin = dist; bidx = k + j; }
    }
  }
  cmin[wv][lane] = bmin;
  cidx[wv][lane] = bidx;
  __syncthreads();
  if (tid < 64) {
    float m = cmin[0][tid];
    int ix = cidx[0][tid];
#pragma unroll
    for (int h = 1; h < 4; ++h) {
      if (cmin[h][tid] < m) { m = cmin[h][tid]; ix = cidx[h][tid]; }
    }
    out[blockIdx.x * 64 + tid] = ix;
  }
}

extern "C" void kernel_launch(void* const* d_in, const int* in_sizes, int n_in,
                              void* d_out, int out_size, void* d_ws, size_t ws_size,
                              hipStream_t stream) {
  const float* Z = (const float*)d_in[0];
  const float* W = (const float*)d_in[1];
  int* out = (int*)d_out;
  char* ws = (char*)d_ws;
  const int npos = in_sizes[0] / DCH;  // 131072

  if (ws_size < (size_t)WS_NEED) {
    vq_fallback<<<npos / 64, 256, 0, stream>>>(Z, W, out);
    return;
  }
  vq_prep<<<8, 64, 0, stream>>>(W, ws);
  vq_main<<<npos / POSB, BLOCK, 0, stream>>>(Z, ws, out);
  vq_rescue<<<RESCUE_BLOCKS, 256, 0, stream>>>(Z, W, ws, out);
}

// Round 19
// 70.131 us; speedup vs baseline: 1.2375x; 1.1085x over previous
//
#include <hip/hip_runtime.h>
#include <stdint.h>

#define DCH 64
#define KC 512
#define HWSZ 4096
#define THETA 1e-4f
#define POSB 512      // positions per block (16 waves x 32)
#define BLOCK 1024
#define PADW 65       // rescue LDS row stride (floats): conflict-free
#define RESCUE_BLOCKS 256

typedef __attribute__((ext_vector_type(8))) short short8v;
typedef __attribute__((ext_vector_type(4))) float floatx4;

// d_ws layout (bytes)
#define WS_WHS   0                        // 512*64 bf16 hi, SWIZZLED rows
#define WS_WLS   65536                    // 512*64 bf16 lo, SWIZZLED rows
#define WS_WNORM 131072                   // 512 f32 (numpy-pairwise exact)
#define WS_CNT   133120                   // int
#define WS_LIST  133184                   // up to 131072 int
#define WS_NEED  (133184 + 131072 * 4)

__device__ __forceinline__ uint16_t f2bf_rne(float x) {
  uint32_t u = __float_as_uint(x);
  uint32_t r = (u + 0x7fffu + ((u >> 16) & 1u)) >> 16;
  return (uint16_t)r;
}
__device__ __forceinline__ float bf2f(uint16_t b) {
  return __uint_as_float(((uint32_t)b) << 16);
}

// numpy pairwise_sum of squares, 64 elems (fp-contract off)
__device__ __forceinline__ float pairwise_sq64(const float* __restrict__ a) {
#pragma clang fp contract(off)
  float r0 = a[0]*a[0], r1 = a[1]*a[1], r2 = a[2]*a[2], r3 = a[3]*a[3];
  float r4 = a[4]*a[4], r5 = a[5]*a[5], r6 = a[6]*a[6], r7 = a[7]*a[7];
#pragma unroll
  for (int i = 8; i < 64; i += 8) {
    r0 += a[i+0]*a[i+0]; r1 += a[i+1]*a[i+1];
    r2 += a[i+2]*a[i+2]; r3 += a[i+3]*a[i+3];
    r4 += a[i+4]*a[i+4]; r5 += a[i+5]*a[i+5];
    r6 += a[i+6]*a[i+6]; r7 += a[i+7]*a[i+7];
  }
  return ((r0+r1)+(r2+r3)) + ((r4+r5)+(r6+r7));
}

// Load 8 Z elements (stride HWSZ), bf16-split element-wise.
__device__ __forceinline__ void load_frag(const float* __restrict__ p,
                                          short8v& vh, short8v& vl) {
#pragma unroll
  for (int j = 0; j < 8; ++j) {
    const float v = p[(size_t)j * HWSZ];
    const uint16_t hb = f2bf_rne(v);
    vh[j] = (short)hb;
    vl[j] = (short)f2bf_rne(v - bf2f(hb));
  }
}

// ---------- prep: W -> bf16 split (SWIZZLED image) + exact wnorm ----------
__global__ __launch_bounds__(64) void vq_prep(const float* __restrict__ W,
                                              char* __restrict__ ws) {
  const int c = blockIdx.x * 64 + threadIdx.x;   // 0..511
  const float* __restrict__ wr = W + c * DCH;
  float a[64];
#pragma unroll
  for (int i = 0; i < 16; ++i) {
    const float4 v = ((const float4*)wr)[i];
    a[4*i+0] = v.x; a[4*i+1] = v.y; a[4*i+2] = v.z; a[4*i+3] = v.w;
  }
  ((float*)(ws + WS_WNORM))[c] = pairwise_sq64(a);
  uint16_t* wh = (uint16_t*)(ws + WS_WHS);
  uint16_t* wl = (uint16_t*)(ws + WS_WLS);
#pragma unroll
  for (int gd = 0; gd < 8; ++gd) {
    short8v vh, vl;
#pragma unroll
    for (int e = 0; e < 8; ++e) {
      const float v = a[gd * 8 + e];
      const uint16_t hb = f2bf_rne(v);
      vh[e] = (short)hb;
      vl[e] = (short)f2bf_rne(v - bf2f(hb));
    }
    const int go = (gd ^ (c & 7)) << 3;   // swizzled granule slot
    *(short8v*)(wh + c * DCH + go) = vh;
    *(short8v*)(wl + c * DCH + go) = vl;
  }
  if (c == 0) *(int*)(ws + WS_CNT) = 0;
}

// ---------- main: MFMA scoring + top-2 gap test (R12, validated 69.7us) ----------
// 1024 threads = 16 waves x 32 positions; grid = 256 = 1 block/CU.
// Whole 128 KB split-W image in LDS once, single barrier, barrier-free loop.
__global__ __launch_bounds__(BLOCK) void vq_main(const float* __restrict__ Z,
                                                 char* __restrict__ ws,
                                                 int* __restrict__ out) {
  __shared__ uint16_t img[65536];   // 128 KB: hi [0,32768), lo [32768,65536)
  __shared__ float wnlds[KC];       // 2 KB

  const int tid = threadIdx.x;
  const int lane = tid & 63;
  const int wv = tid >> 6;                // 0..15
  const int csub = lane & 15;
  const int gsub = lane >> 4;
  const int nbase = blockIdx.x * POSB;

  const char* __restrict__ img_src = (const char*)ws;  // 128 KB contiguous
  const float* __restrict__ wnorm = (const float*)(ws + WS_WNORM);
  int* cnt = (int*)(ws + WS_CNT);
  int* list = (int*)(ws + WS_LIST);

#pragma unroll
  for (int r = 0; r < 8; ++r) {
    const int base = r * 16384 + wv * 1024;   // wave-uniform LDS byte base
    __builtin_amdgcn_global_load_lds((const uint32_t*)(img_src + base + lane * 16),
                                     (uint32_t*)((char*)img + base), 16, 0, 0);
  }
  if (tid < 128) {
    const int base = wv * 1024;
    __builtin_amdgcn_global_load_lds((const uint32_t*)((const char*)wnorm + base + lane * 16),
                                     (uint32_t*)((char*)wnlds + base), 16, 0, 0);
  }

  short8v ahA0, ahA1, alA0, alA1, ahB0, ahB1, alB0, alB1;
  {
    const int b = nbase >> 12;
    const int hw0 = nbase & 4095;
    const float* zb = Z + (size_t)b * DCH * HWSZ + hw0 + wv * 32 + csub;
    const int dbase = gsub * 8;
    load_frag(zb + (size_t)(dbase +  0) * HWSZ,      ahA0, alA0);
    load_frag(zb + (size_t)(dbase + 32) * HWSZ,      ahA1, alA1);
    load_frag(zb + (size_t)(dbase +  0) * HWSZ + 16, ahB0, alB0);
    load_frag(zb + (size_t)(dbase + 32) * HWSZ + 16, ahB1, alB1);
  }

  float m1A[4], m2A[4], m1B[4], m2B[4];
  int i1A[4], i1B[4];
#pragma unroll
  for (int r = 0; r < 4; ++r) {
    m1A[r] = 3.4e38f; m2A[r] = 3.4e38f; i1A[r] = 0;
    m1B[r] = 3.4e38f; m2B[r] = 3.4e38f; i1B[r] = 0;
  }

  __syncthreads();  // image + wnorm ready; ONLY barrier.

  const uint16_t* __restrict__ whl = img;            // hi
  const uint16_t* __restrict__ wll = img + 32768;    // lo

  // loop-invariant swizzle slots (cloc&7 == csub&7 since kt*16 % 8 == 0)
  const int go0 = (gsub ^ (csub & 7)) << 3;
  const int go1 = ((4 + gsub) ^ (csub & 7)) << 3;

#pragma unroll 8
  for (int kt = 0; kt < KC / 16; ++kt) {
    const int cloc = kt * 16 + csub;
    const float wn = wnlds[cloc];
    const short8v bh0 = *(const short8v*)&whl[cloc * DCH + go0];
    const short8v bh1 = *(const short8v*)&whl[cloc * DCH + go1];
    const short8v bl0 = *(const short8v*)&wll[cloc * DCH + go0];
    const short8v bl1 = *(const short8v*)&wll[cloc * DCH + go1];
    const floatx4 zz = {0.f, 0.f, 0.f, 0.f};
    // 3 independent 2-deep chains per set (hh, h*lo, lo*h)
    floatx4 cA1 = __builtin_amdgcn_mfma_f32_16x16x32_bf16(ahA0, bh0, zz, 0, 0, 0);
    floatx4 cB1 = __builtin_amdgcn_mfma_f32_16x16x32_bf16(ahB0, bh0, zz, 0, 0, 0);
    floatx4 cA2 = __builtin_amdgcn_mfma_f32_16x16x32_bf16(ahA0, bl0, zz, 0, 0, 0);
    floatx4 cB2 = __builtin_amdgcn_mfma_f32_16x16x32_bf16(ahB0, bl0, zz, 0, 0, 0);
    floatx4 cA3 = __builtin_amdgcn_mfma_f32_16x16x32_bf16(alA0, bh0, zz, 0, 0, 0);
    floatx4 cB3 = __builtin_amdgcn_mfma_f32_16x16x32_bf16(alB0, bh0, zz, 0, 0, 0);
    cA1 = __builtin_amdgcn_mfma_f32_16x16x32_bf16(ahA1, bh1, cA1, 0, 0, 0);
    cB1 = __builtin_amdgcn_mfma_f32_16x16x32_bf16(ahB1, bh1, cB1, 0, 0, 0);
    cA2 = __builtin_amdgcn_mfma_f32_16x16x32_bf16(ahA1, bl1, cA2, 0, 0, 0);
    cB2 = __builtin_amdgcn_mfma_f32_16x16x32_bf16(ahB1, bl1, cB2, 0, 0, 0);
    cA3 = __builtin_amdgcn_mfma_f32_16x16x32_bf16(alA1, bh1, cA3, 0, 0, 0);
    cB3 = __builtin_amdgcn_mfma_f32_16x16x32_bf16(alB1, bh1, cB3, 0, 0, 0);
#pragma unroll
    for (int r = 0; r < 4; ++r) {
      const float sA = fmaf(-2.0f, (cA1[r] + cA2[r]) + cA3[r], wn);
      i1A[r] = (sA < m1A[r]) ? cloc : i1A[r];
      m2A[r] = fminf(fmaxf(sA, m1A[r]), m2A[r]);
      m1A[r] = fminf(sA, m1A[r]);
      const float sB = fmaf(-2.0f, (cB1[r] + cB2[r]) + cB3[r], wn);
      i1B[r] = (sB < m1B[r]) ? cloc : i1B[r];
      m2B[r] = fminf(fmaxf(sB, m1B[r]), m2B[r]);
      m1B[r] = fminf(sB, m1B[r]);
    }
  }

#pragma unroll
  for (int off = 1; off < 16; off <<= 1) {
#pragma unroll
    for (int r = 0; r < 4; ++r) {
      {
        const float om1 = __shfl_xor(m1A[r], off, 64);
        const float om2 = __shfl_xor(m2A[r], off, 64);
        const int oi = __shfl_xor(i1A[r], off, 64);
        const float nm2 = fminf(fmaxf(m1A[r], om1), fminf(m2A[r], om2));
        i1A[r] = (om1 < m1A[r]) ? oi : i1A[r];
        m1A[r] = fminf(m1A[r], om1);
        m2A[r] = nm2;
      }
      {
        const float om1 = __shfl_xor(m1B[r], off, 64);
        const float om2 = __shfl_xor(m2B[r], off, 64);
        const int oi = __shfl_xor(i1B[r], off, 64);
        const float nm2 = fminf(fmaxf(m1B[r], om1), fminf(m2B[r], om2));
        i1B[r] = (om1 < m1B[r]) ? oi : i1B[r];
        m1B[r] = fminf(m1B[r], om1);
        m2B[r] = nm2;
      }
    }
  }
  if (csub == 0) {
#pragma unroll
    for (int r = 0; r < 4; ++r) {
      const int posA = nbase + wv * 32 + gsub * 4 + r;
      out[posA] = i1A[r];
      if (!(m2A[r] - m1A[r] > THETA)) {
        const int slot = atomicAdd(cnt, 1);
        list[slot] = posA;
      }
      const int posB = posA + 16;
      out[posB] = i1B[r];
      if (!(m2B[r] - m1B[r] > THETA)) {
        const int slot = atomicAdd(cnt, 1);
        list[slot] = posB;
      }
    }
  }
}

// ---------- rescue: LDS-staged W, conflict-free; bit-exact numpy order ----------
__global__ __launch_bounds__(256) void vq_rescue(const float* __restrict__ Z,
                                                 const float* __restrict__ W,
                                                 char* __restrict__ ws,
                                                 int* __restrict__ out) {
  __shared__ float wt[KC * PADW];   // 512 x 65 floats = 133,120 B
  const int cnt = *(const int*)(ws + WS_CNT);
  if (blockIdx.x * 4 >= cnt) return;   // block-uniform early out (before staging)

  const int lane = threadIdx.x & 63;
  const int wv = threadIdx.x >> 6;     // 0..3
  const int wvg = blockIdx.x * 4 + wv;
  const int* list = (const int*)(ws + WS_LIST);
  const float* wnorm = (const float*)(ws + WS_WNORM);

  for (int c = wv; c < KC; c += 4) {
    wt[c * PADW + lane] = W[c * DCH + lane];
  }
  __syncthreads();

  for (int j = wvg; j < cnt; j += RESCUE_BLOCKS * 4) {
    const int pos = list[j];
    const int b = pos >> 12, hw = pos & 4095;
    float z[DCH];
    const float* zb = Z + ((size_t)b * DCH) * HWSZ + hw;
#pragma unroll
    for (int d = 0; d < DCH; ++d) z[d] = zb[(size_t)d * HWSZ];
    const float znorm = pairwise_sq64(z);
    float bm = 3.4e38f;
    int bi = 0;
#pragma unroll 1
    for (int j2 = 0; j2 < 8; ++j2) {
      const int k = j2 * 64 + lane;
      const float* __restrict__ wrow = &wt[k * PADW];  // lane-own row
      float acc = 0.f;
#pragma unroll
      for (int d = 0; d < DCH; ++d) acc = fmaf(z[d], wrow[d], acc);
      const float dist = (znorm - 2.0f * acc) + wnorm[k];
      if (dist < bm) { bm = dist; bi = k; }  // ascending k per lane
    }
#pragma unroll
    for (int off = 32; off >= 1; off >>= 1) {
      const float ov = __shfl_xor(bm, off, 64);
      const int oi = __shfl_xor(bi, off, 64);
      if (ov < bm || (ov == bm && oi < bi)) { bm = ov; bi = oi; }
    }
    if (lane == 0) out[pos] = bi;
  }
}

// ---------- fallback (R4, known exact) if ws too small ----------
__global__ __launch_bounds__(256, 4) void vq_fallback(const float* __restrict__ Z,
                                                      const float* __restrict__ W,
                                                      int* __restrict__ out) {
  __shared__ float wnorm[KC];
  __shared__ float cmin[4][64];
  __shared__ int cidx[4][64];
  const int tid = threadIdx.x;
  for (int c = tid; c < KC; c += 256) wnorm[c] = pairwise_sq64(W + c * DCH);
  const int lane = tid & 63;
  const int wv = __builtin_amdgcn_readfirstlane(tid >> 6);
  const int n = blockIdx.x * 64 + lane;
  float z[DCH];
  {
    const int b = n >> 12, hw = n & 4095;
    const float* zbase = Z + ((size_t)b * DCH) * HWSZ + hw;
#pragma unroll
    for (int d = 0; d < DCH; ++d) z[d] = zbase[(size_t)d * HWSZ];
  }
  const float znorm = pairwise_sq64(z);
  __syncthreads();
  float bmin = 3.4e38f;
  int bidx = 0;
  const int k0 = wv * 128;
#pragma unroll 1
  for (int kk = 0; kk < 128; kk += 8) {
    const int k = k0 + kk;
    const float* wr = W + (size_t)k * DCH;
    float acc[8];
#pragma unroll
    for (int j = 0; j < 8; ++j) acc[j] = 0.0f;
#pragma unroll
    for (int d = 0; d < DCH; ++d) {
      const float zd = z[d];
#pragma unroll
      for (int j = 0; j < 8; ++j) acc[j] = fmaf(zd, wr[j * DCH + d], acc[j]);
    }
#pragma unroll
    for (int j = 0; j < 8; ++j) {
      const float dist = (znorm - 2.0f * acc[j]) + wnorm[k + j];
      if (dist < bmin) { bmin = dist; bidx = k + j; }
    }
  }
  cmin[wv][lane] = bmin;
  cidx[wv][lane] = bidx;
  __syncthreads();
  if (tid < 64) {
    float m = cmin[0][tid];
    int ix = cidx[0][tid];
#pragma unroll
    for (int h = 1; h < 4; ++h) {
      if (cmin[h][tid] < m) { m = cmin[h][tid]; ix = cidx[h][tid]; }
    }
    out[blockIdx.x * 64 + tid] = ix;
  }
}

extern "C" void kernel_launch(void* const* d_in, const int* in_sizes, int n_in,
                              void* d_out, int out_size, void* d_ws, size_t ws_size,
                              hipStream_t stream) {
  const float* Z = (const float*)d_in[0];
  const float* W = (const float*)d_in[1];
  int* out = (int*)d_out;
  char* ws = (char*)d_ws;
  const int npos = in_sizes[0] / DCH;  // 131072

  if (ws_size < (size_t)WS_NEED) {
    vq_fallback<<<npos / 64, 256, 0, stream>>>(Z, W, out);
    return;
  }
  vq_prep<<<8, 64, 0, stream>>>(W, ws);
  vq_main<<<npos / POSB, BLOCK, 0, stream>>>(Z, ws, out);
  vq_rescue<<<RESCUE_BLOCKS, 256, 0, stream>>>(Z, W, ws, out);
}